// Round 1
// baseline (233.350 us; speedup 1.0000x reference)
//
#include <hip/hip_runtime.h>
#include <math.h>

#define B_  16
#define C_  512
#define A_  64
#define CV  448     // C - A (value / z_img dims)
#define G_  256
#define HW  256
#define TS  16      // value tile size along s

// ---------------- Kernel 1: spatial mean pool  z[b,c] = mean(Z_img[b,c,:,:]) ----
__global__ __launch_bounds__(256) void meanpool_kernel(const float* __restrict__ Zimg,
                                                       float* __restrict__ z) {
  int row  = (blockIdx.x << 2) + (threadIdx.x >> 6);   // b*C + c
  int lane = threadIdx.x & 63;
  const float4* p = (const float4*)(Zimg + (size_t)row * HW);
  float4 v = p[lane];                                  // 64 lanes x float4 = 256 floats
  float s = (v.x + v.y) + (v.z + v.w);
  #pragma unroll
  for (int off = 32; off > 0; off >>= 1)
    s += __shfl_down(s, off, 64);
  if (lane == 0) z[row] = s * (1.0f / HW);
}

// ---------------- Kernel 2: per-group attention ------------------------------
__global__ __launch_bounds__(256) void attn_kernel(
    const float* __restrict__ Zsnd,
    const int*   __restrict__ pad_idx,
    const float* __restrict__ z,
    float*       __restrict__ Mimg,
    float*       __restrict__ Msnd,
    int Smax, int N)
{
  const int g    = blockIdx.x;
  const int t    = threadIdx.x;
  const int lane = t & 63;
  const int wave = t >> 6;

  __shared__ float qs[B_ * A_];       // 4 KB   queries z[:,448:512]
  __shared__ int   idxs[256];         // 1 KB   gather indices (-1 = invalid)
  __shared__ float attnB[B_ * 256];   // 16 KB  attn weights, [b][s] layout
  __shared__ float vt[TS * CV];       // 28 KB  value tile [ss][448]
  __shared__ float red[4 * B_];
  __shared__ float red2[4 * B_];
  __shared__ int   redi[4];

  // ---- pad_idx row + validity (valid <=> j==0 || idx!=0; prefix-contiguous) ----
  int myidx = -1;
  if (t < Smax) {
    int v = pad_idx[(size_t)g * Smax + t];
    bool ok = ((t == 0) || (v != 0)) && (v >= 0) && (v < N);
    myidx = ok ? v : -1;
  }
  idxs[t] = myidx;
  const bool valid = (myidx >= 0);

  // ---- stage q into LDS ----
  {
    int b = t >> 4, a4 = t & 15;
    float4 qv = *(const float4*)(z + b * C_ + CV + a4 * 4);
    *(float4*)(qs + b * A_ + a4 * 4) = qv;
  }

  // ---- M_img[g] = broadcast z_img (independent of attention; issue early) ----
  #pragma unroll
  for (int i = 0; i < 7; i++) {
    int li = i * 256 + t;
    int b = li / 112, c4 = li % 112;
    float4 zv = *(const float4*)(z + b * C_ + c4 * 4);
    *(float4*)(Mimg + (size_t)g * (B_ * CV) + b * CV + c4 * 4) = zv;
  }

  // ---- s_g = number of valid rows (valid prefix) ----
  int sgv = valid ? (t + 1) : 0;
  #pragma unroll
  for (int off = 32; off > 0; off >>= 1)
    sgv = max(sgv, __shfl_xor(sgv, off, 64));
  if (lane == 0) redi[wave] = sgv;

  __syncthreads();
  const int sg = max(max(redi[0], redi[1]), max(redi[2], redi[3]));

  // ---- pass 1: thread t computes scores[b][s=t] for all b ----
  float sc[B_];
  #pragma unroll
  for (int b = 0; b < B_; b++) sc[b] = 0.0f;
  {
    const float* krow = Zsnd + (size_t)(valid ? myidx : 0) * C_ + CV;
    #pragma unroll
    for (int a4 = 0; a4 < 16; a4++) {
      float4 kv = *(const float4*)(krow + a4 * 4);       // per-thread key chunk
      #pragma unroll
      for (int b = 0; b < B_; b++) {
        float4 qv = *(const float4*)(qs + b * A_ + a4 * 4); // wave-uniform broadcast
        sc[b] += qv.x * kv.x + qv.y * kv.y + qv.z * kv.z + qv.w * kv.w;
      }
    }
  }

  // ---- softmax over s (= over threads): butterfly + cross-wave LDS combine ----
  float mx[B_];
  #pragma unroll
  for (int b = 0; b < B_; b++) {
    float v = valid ? sc[b] : -INFINITY;
    #pragma unroll
    for (int off = 32; off > 0; off >>= 1)
      v = fmaxf(v, __shfl_xor(v, off, 64));
    mx[b] = v;
  }
  if (lane == 0) {
    #pragma unroll
    for (int b = 0; b < B_; b++) red[wave * B_ + b] = mx[b];
  }
  __syncthreads();

  float ex[B_];
  float sm[B_];
  #pragma unroll
  for (int b = 0; b < B_; b++) {
    float gm = fmaxf(fmaxf(red[0 * B_ + b], red[1 * B_ + b]),
                     fmaxf(red[2 * B_ + b], red[3 * B_ + b]));
    float e = valid ? __expf(sc[b] - gm) : 0.0f;
    ex[b] = e;
    #pragma unroll
    for (int off = 32; off > 0; off >>= 1)
      e += __shfl_xor(e, off, 64);
    sm[b] = e;
  }
  if (lane == 0) {
    #pragma unroll
    for (int b = 0; b < B_; b++) red2[wave * B_ + b] = sm[b];
  }
  __syncthreads();

  #pragma unroll
  for (int b = 0; b < B_; b++) {
    float gs = (red2[0 * B_ + b] + red2[1 * B_ + b]) +
               (red2[2 * B_ + b] + red2[3 * B_ + b]);
    attnB[b * 256 + t] = ex[b] / gs;   // conflict-free stride-1 store
  }
  __syncthreads();

  // ---- pass 2: M_snd[g,b,:] = sum_s attn[b][s] * value[s][:] ----
  // wave owns b in [4*wave, 4*wave+4); lane owns c = 4*lane and c = 256 + 4*lane (<448)
  const int b0 = wave * 4;
  float4 acc[4][2];
  #pragma unroll
  for (int i = 0; i < 4; i++) {
    acc[i][0] = make_float4(0.f, 0.f, 0.f, 0.f);
    acc[i][1] = make_float4(0.f, 0.f, 0.f, 0.f);
  }

  float4 pre[7];
  // prefetch tile 0
  #pragma unroll
  for (int i = 0; i < 7; i++) {
    int li = i * 256 + t;
    int ss = li / 112, c4 = li % 112;
    int s = ss;   // s0 == 0
    int idx = (s < Smax) ? idxs[s] : -1;
    if (idx < 0) idx = 0;
    pre[i] = *(const float4*)(Zsnd + (size_t)idx * C_ + c4 * 4);
  }

  for (int s0 = 0; s0 < sg; s0 += TS) {
    __syncthreads();                       // prior tile's compute done
    #pragma unroll
    for (int i = 0; i < 7; i++) {          // pre -> LDS (vt offset == li*4 floats)
      int li = i * 256 + t;
      *(float4*)(vt + li * 4) = pre[i];
    }
    __syncthreads();                       // vt ready
    // issue next tile's prefetch AFTER the barrier so it overlaps compute
    if (s0 + TS < sg) {
      #pragma unroll
      for (int i = 0; i < 7; i++) {
        int li = i * 256 + t;
        int ss = li / 112, c4 = li % 112;
        int s = s0 + TS + ss;
        int idx = (s < Smax) ? idxs[s] : -1;
        if (idx < 0) idx = 0;
        pre[i] = *(const float4*)(Zsnd + (size_t)idx * C_ + c4 * 4);
      }
    }
    int send = min(TS, sg - s0);
    for (int ss = 0; ss < send; ss++) {
      float a0 = attnB[(b0 + 0) * 256 + s0 + ss];   // wave-uniform broadcasts
      float a1 = attnB[(b0 + 1) * 256 + s0 + ss];
      float a2 = attnB[(b0 + 2) * 256 + s0 + ss];
      float a3 = attnB[(b0 + 3) * 256 + s0 + ss];
      const float* vrow = vt + ss * CV;
      float4 v0 = *(const float4*)(vrow + lane * 4);
      acc[0][0].x += a0 * v0.x; acc[0][0].y += a0 * v0.y; acc[0][0].z += a0 * v0.z; acc[0][0].w += a0 * v0.w;
      acc[1][0].x += a1 * v0.x; acc[1][0].y += a1 * v0.y; acc[1][0].z += a1 * v0.z; acc[1][0].w += a1 * v0.w;
      acc[2][0].x += a2 * v0.x; acc[2][0].y += a2 * v0.y; acc[2][0].z += a2 * v0.z; acc[2][0].w += a2 * v0.w;
      acc[3][0].x += a3 * v0.x; acc[3][0].y += a3 * v0.y; acc[3][0].z += a3 * v0.z; acc[3][0].w += a3 * v0.w;
      if (lane < 48) {
        float4 v1 = *(const float4*)(vrow + 256 + lane * 4);
        acc[0][1].x += a0 * v1.x; acc[0][1].y += a0 * v1.y; acc[0][1].z += a0 * v1.z; acc[0][1].w += a0 * v1.w;
        acc[1][1].x += a1 * v1.x; acc[1][1].y += a1 * v1.y; acc[1][1].z += a1 * v1.z; acc[1][1].w += a1 * v1.w;
        acc[2][1].x += a2 * v1.x; acc[2][1].y += a2 * v1.y; acc[2][1].z += a2 * v1.z; acc[2][1].w += a2 * v1.w;
        acc[3][1].x += a3 * v1.x; acc[3][1].y += a3 * v1.y; acc[3][1].z += a3 * v1.z; acc[3][1].w += a3 * v1.w;
      }
    }
  }

  // ---- store M_snd ----
  #pragma unroll
  for (int i = 0; i < 4; i++) {
    float* orow = Msnd + (size_t)g * (B_ * CV) + (size_t)(b0 + i) * CV;
    *(float4*)(orow + lane * 4) = acc[i][0];
    if (lane < 48) *(float4*)(orow + 256 + lane * 4) = acc[i][1];
  }
}

extern "C" void kernel_launch(void* const* d_in, const int* in_sizes, int n_in,
                              void* d_out, int out_size, void* d_ws, size_t ws_size,
                              hipStream_t stream) {
  const float* Zimg   = (const float*)d_in[0];
  const float* Zsnd   = (const float*)d_in[1];
  const int*   padidx = (const int*)d_in[2];
  // d_in[3] = pad_mask (unused; validity derived from pad_idx)
  // d_in[4] = attn_dims (constant 64)

  const int N    = in_sizes[1] / C_;     // rows in Z_snd
  const int Smax = in_sizes[2] / G_;     // padded sequence length

  float* z    = (float*)d_ws;            // B*C fp32 scratch
  float* Mimg = (float*)d_out;
  float* Msnd = Mimg + (size_t)G_ * B_ * CV;

  meanpool_kernel<<<(B_ * C_) / 4, 256, 0, stream>>>(Zimg, z);
  attn_kernel<<<G_, 256, 0, stream>>>(Zsnd, padidx, z, Mimg, Msnd, Smax, N);
}

// Round 2
// 232.536 us; speedup vs baseline: 1.0035x; 1.0035x over previous
//
#include <hip/hip_runtime.h>
#include <math.h>

#define B_  16
#define C_  512
#define A_  64
#define CV  448     // C - A (value / z_img dims)
#define G_  256
#define HW  256
#define SMX 256     // padded S (Smax); asserted via launch math

// ---------------- Kernel 1: spatial mean pool  z[b,c] = mean(Z_img[b,c,:,:]) ----
__global__ __launch_bounds__(256) void meanpool_kernel(const float* __restrict__ Zimg,
                                                       float* __restrict__ z) {
  int row  = (blockIdx.x << 2) + (threadIdx.x >> 6);   // b*C + c
  int lane = threadIdx.x & 63;
  const float4* p = (const float4*)(Zimg + (size_t)row * HW);
  float4 v = p[lane];                                  // 64 lanes x float4 = 256 floats
  float s = (v.x + v.y) + (v.z + v.w);
  #pragma unroll
  for (int off = 32; off > 0; off >>= 1)
    s += __shfl_down(s, off, 64);
  if (lane == 0) z[row] = s * (1.0f / HW);
}

// ---------------- Kernel 2: scores + softmax -> attn weights in ws ------------
// attnW layout: [g][s][b], 16 floats per s, 4096 floats per g.
__global__ __launch_bounds__(256) void score_kernel(
    const float* __restrict__ Zsnd,
    const int*   __restrict__ pad_idx,
    const float* __restrict__ z,
    float*       __restrict__ attnW,
    int Smax, int N)
{
  const int g    = blockIdx.x;
  const int t    = threadIdx.x;
  const int lane = t & 63;
  const int wave = t >> 6;

  __shared__ float qs[B_ * A_];
  __shared__ float red[4 * B_];
  __shared__ float red2[4 * B_];

  // validity from pad_idx (valid <=> j==0 || idx!=0; prefix-contiguous)
  int myidx = -1;
  if (t < Smax) {
    int v = pad_idx[(size_t)g * Smax + t];
    bool ok = ((t == 0) || (v != 0)) && (v >= 0) && (v < N);
    myidx = ok ? v : -1;
  }
  const bool valid = (myidx >= 0);

  {
    int b = t >> 4, a4 = t & 15;
    *(float4*)(qs + b * A_ + a4 * 4) = *(const float4*)(z + b * C_ + CV + a4 * 4);
  }
  __syncthreads();

  // scores: thread t = s, all 16 b
  float sc[B_];
  #pragma unroll
  for (int b = 0; b < B_; b++) sc[b] = 0.0f;
  {
    const float* krow = Zsnd + (size_t)(valid ? myidx : 0) * C_ + CV;
    #pragma unroll
    for (int a4 = 0; a4 < 16; a4++) {
      float4 kv = *(const float4*)(krow + a4 * 4);
      #pragma unroll
      for (int b = 0; b < B_; b++) {
        float4 qv = *(const float4*)(qs + b * A_ + a4 * 4);
        sc[b] += qv.x * kv.x + qv.y * kv.y + qv.z * kv.z + qv.w * kv.w;
      }
    }
  }

  // softmax over s (threads): butterfly + cross-wave LDS combine
  #pragma unroll
  for (int b = 0; b < B_; b++) {
    float v = valid ? sc[b] : -INFINITY;
    #pragma unroll
    for (int off = 32; off > 0; off >>= 1)
      v = fmaxf(v, __shfl_xor(v, off, 64));
    if (lane == 0) red[wave * B_ + b] = v;
  }
  __syncthreads();

  float ex[B_], sm[B_];
  #pragma unroll
  for (int b = 0; b < B_; b++) {
    float gm = fmaxf(fmaxf(red[0 * B_ + b], red[1 * B_ + b]),
                     fmaxf(red[2 * B_ + b], red[3 * B_ + b]));
    float e = valid ? __expf(sc[b] - gm) : 0.0f;
    ex[b] = e;
    #pragma unroll
    for (int off = 32; off > 0; off >>= 1)
      e += __shfl_xor(e, off, 64);
    sm[b] = e;
  }
  if (lane == 0) {
    #pragma unroll
    for (int b = 0; b < B_; b++) red2[wave * B_ + b] = sm[b];
  }
  __syncthreads();

  float* orow = attnW + ((size_t)g * SMX + t) * B_;
  #pragma unroll
  for (int b4 = 0; b4 < 4; b4++) {
    float4 o;
    float g0 = (red2[0 * B_ + b4 * 4 + 0] + red2[1 * B_ + b4 * 4 + 0]) + (red2[2 * B_ + b4 * 4 + 0] + red2[3 * B_ + b4 * 4 + 0]);
    float g1 = (red2[0 * B_ + b4 * 4 + 1] + red2[1 * B_ + b4 * 4 + 1]) + (red2[2 * B_ + b4 * 4 + 1] + red2[3 * B_ + b4 * 4 + 1]);
    float g2 = (red2[0 * B_ + b4 * 4 + 2] + red2[1 * B_ + b4 * 4 + 2]) + (red2[2 * B_ + b4 * 4 + 2] + red2[3 * B_ + b4 * 4 + 2]);
    float g3 = (red2[0 * B_ + b4 * 4 + 3] + red2[1 * B_ + b4 * 4 + 3]) + (red2[2 * B_ + b4 * 4 + 3] + red2[3 * B_ + b4 * 4 + 3]);
    o.x = ex[b4 * 4 + 0] / g0;
    o.y = ex[b4 * 4 + 1] / g1;
    o.z = ex[b4 * 4 + 2] / g2;
    o.w = ex[b4 * 4 + 3] / g3;
    *(float4*)(orow + b4 * 4) = o;
  }
}

// ---------------- Kernel 3: weighted value sum + M_img broadcast --------------
// grid = G*4; block bid -> g = bid>>2, column chunk cs = bid&3 (128,128,128,64).
// Wave owns 4 b rows; lane owns a float2 of c. No barrier in the main loop.
__global__ __launch_bounds__(256) void out_kernel(
    const float* __restrict__ Zsnd,
    const int*   __restrict__ pad_idx,
    const float* __restrict__ attnW,
    const float* __restrict__ z,
    float*       __restrict__ Mimg,
    float*       __restrict__ Msnd,
    int Smax, int N)
{
  const int bid  = blockIdx.x;
  const int g    = bid >> 2;
  const int cs   = bid & 3;
  const int c0   = cs * 128;
  const int w    = (cs == 3) ? 64 : 128;
  const int t    = threadIdx.x;
  const int lane = t & 63;
  const int wave = t >> 6;

  __shared__ int   idxs[SMX];
  __shared__ float attnS[SMX * B_];   // 16 KB
  __shared__ int   redi[4];

  int myidx = 0, sgv = 0;
  if (t < Smax) {
    int v = pad_idx[(size_t)g * Smax + t];
    bool ok = ((t == 0) || (v != 0)) && (v >= 0) && (v < N);
    myidx = ok ? v : 0;
    sgv   = ok ? (t + 1) : 0;
  }
  idxs[t] = myidx;
  #pragma unroll
  for (int off = 32; off > 0; off >>= 1)
    sgv = max(sgv, __shfl_xor(sgv, off, 64));
  if (lane == 0) redi[wave] = sgv;

  // stage attn slice [256][16] into LDS (coalesced b128)
  #pragma unroll
  for (int i = 0; i < 4; i++) {
    int li = i * 256 + t;
    *(float4*)(attnS + li * 4) = *(const float4*)(attnW + (size_t)g * (SMX * B_) + li * 4);
  }

  // M_img stripe: Mimg[g, b, c0:c0+w] = z[b, c0:c0+w]
  if (w == 128) {
    #pragma unroll
    for (int i = 0; i < 2; i++) {
      int li = i * 256 + t;          // < 512 float4s
      int b = li >> 5, c4 = li & 31;
      *(float4*)(Mimg + (size_t)g * (B_ * CV) + b * CV + c0 + c4 * 4) =
          *(const float4*)(z + b * C_ + c0 + c4 * 4);
    }
  } else {
    int b = t >> 4, c4 = t & 15;     // 256 float4s
    *(float4*)(Mimg + (size_t)g * (B_ * CV) + b * CV + c0 + c4 * 4) =
        *(const float4*)(z + b * C_ + c0 + c4 * 4);
  }

  __syncthreads();
  const int sg  = max(max(redi[0], redi[1]), max(redi[2], redi[3]));
  const int sg4 = (sg + 3) & ~3;

  const int b0 = wave * 4;
  const float* vbase = Zsnd + c0 + lane * 2;   // + idx*C_  (always in-row: c0+126 <= 510)
  float a00 = 0.f, a01 = 0.f, a10 = 0.f, a11 = 0.f;
  float a20 = 0.f, a21 = 0.f, a30 = 0.f, a31 = 0.f;

  for (int s = 0; s < sg4; s += 4) {
    float2 v[4];
    #pragma unroll
    for (int j = 0; j < 4; j++) {
      int idx = idxs[s + j];
      v[j] = *(const float2*)(vbase + (size_t)idx * C_);
    }
    #pragma unroll
    for (int j = 0; j < 4; j++) {
      float4 at = *(const float4*)(attnS + (s + j) * B_ + b0);  // wave-uniform broadcast
      float2 vv = v[j];
      a00 += at.x * vv.x; a01 += at.x * vv.y;
      a10 += at.y * vv.x; a11 += at.y * vv.y;
      a20 += at.z * vv.x; a21 += at.z * vv.y;
      a30 += at.w * vv.x; a31 += at.w * vv.y;
    }
  }

  if (2 * lane < w) {
    float* obase = Msnd + (size_t)g * (B_ * CV) + (size_t)b0 * CV + c0 + 2 * lane;
    *(float2*)(obase + 0 * CV) = make_float2(a00, a01);
    *(float2*)(obase + 1 * CV) = make_float2(a10, a11);
    *(float2*)(obase + 2 * CV) = make_float2(a20, a21);
    *(float2*)(obase + 3 * CV) = make_float2(a30, a31);
  }
}

extern "C" void kernel_launch(void* const* d_in, const int* in_sizes, int n_in,
                              void* d_out, int out_size, void* d_ws, size_t ws_size,
                              hipStream_t stream) {
  const float* Zimg   = (const float*)d_in[0];
  const float* Zsnd   = (const float*)d_in[1];
  const int*   padidx = (const int*)d_in[2];
  // d_in[3] = pad_mask (unused; validity derived from pad_idx)
  // d_in[4] = attn_dims (constant 64)

  const int N    = in_sizes[1] / C_;     // rows in Z_snd
  const int Smax = in_sizes[2] / G_;     // padded sequence length (== 256)

  float* z     = (float*)d_ws;                       // B*C fp32
  float* attnW = z + B_ * C_;                        // G*SMX*B_ fp32 = 4 MB
  float* Mimg  = (float*)d_out;
  float* Msnd  = Mimg + (size_t)G_ * B_ * CV;

  meanpool_kernel<<<(B_ * C_) / 4, 256, 0, stream>>>(Zimg, z);
  score_kernel<<<G_, 256, 0, stream>>>(Zsnd, padidx, z, attnW, Smax, N);
  out_kernel<<<G_ * 4, 256, 0, stream>>>(Zsnd, padidx, attnW, z, Mimg, Msnd, Smax, N);
}

// Round 3
// 217.242 us; speedup vs baseline: 1.0741x; 1.0704x over previous
//
#include <hip/hip_runtime.h>
#include <math.h>

#define B_  16
#define C_  512
#define A_  64
#define CV  448     // C - A (value / z_img dims)
#define G_  256
#define HW  256
#define SMX 256     // padded S (Smax)

// ---------------- Kernel 1: spatial mean pool  z[b,c] = mean(Z_img[b,c,:,:]) ----
__global__ __launch_bounds__(256) void meanpool_kernel(const float* __restrict__ Zimg,
                                                       float* __restrict__ z) {
  int row  = (blockIdx.x << 2) + (threadIdx.x >> 6);   // b*C + c
  int lane = threadIdx.x & 63;
  const float4* p = (const float4*)(Zimg + (size_t)row * HW);
  float4 v = p[lane];
  float s = (v.x + v.y) + (v.z + v.w);
  #pragma unroll
  for (int off = 32; off > 0; off >>= 1)
    s += __shfl_down(s, off, 64);
  if (lane == 0) z[row] = s * (1.0f / HW);
}

// ---------------- Kernel 2: scores + softmax -> attn weights ------------------
// attnW layout: [g][b][s]  (b-major; coalesced dword stores across t=s).
// Round-1-proven low-register structure (80 VGPR) — avoid scratch-array spill.
__global__ __launch_bounds__(256) void score_kernel(
    const float* __restrict__ Zsnd,
    const int*   __restrict__ pad_idx,
    const float* __restrict__ z,
    float*       __restrict__ attnW,
    int Smax, int N)
{
  const int g    = blockIdx.x;
  const int t    = threadIdx.x;
  const int lane = t & 63;
  const int wave = t >> 6;

  __shared__ float qs[B_ * A_];
  __shared__ float red[4 * B_];
  __shared__ float red2[4 * B_];

  // validity from pad_idx (valid <=> j==0 || idx!=0; prefix-contiguous)
  int myidx = -1;
  if (t < Smax) {
    int v = pad_idx[(size_t)g * Smax + t];
    bool ok = ((t == 0) || (v != 0)) && (v >= 0) && (v < N);
    myidx = ok ? v : -1;
  }
  const bool valid = (myidx >= 0);

  {
    int b = t >> 4, a4 = t & 15;
    *(float4*)(qs + b * A_ + a4 * 4) = *(const float4*)(z + b * C_ + CV + a4 * 4);
  }
  __syncthreads();

  // scores: thread t = s, all 16 b
  float sc[B_];
  #pragma unroll
  for (int b = 0; b < B_; b++) sc[b] = 0.0f;
  {
    const float* krow = Zsnd + (size_t)(valid ? myidx : 0) * C_ + CV;
    #pragma unroll
    for (int a4 = 0; a4 < 16; a4++) {
      float4 kv = *(const float4*)(krow + a4 * 4);
      #pragma unroll
      for (int b = 0; b < B_; b++) {
        float4 qv = *(const float4*)(qs + b * A_ + a4 * 4);
        sc[b] += qv.x * kv.x + qv.y * kv.y + qv.z * kv.z + qv.w * kv.w;
      }
    }
  }

  // softmax over s (threads): butterfly + cross-wave LDS combine
  #pragma unroll
  for (int b = 0; b < B_; b++) {
    float v = valid ? sc[b] : -INFINITY;
    #pragma unroll
    for (int off = 32; off > 0; off >>= 1)
      v = fmaxf(v, __shfl_xor(v, off, 64));
    if (lane == 0) red[wave * B_ + b] = v;
  }
  __syncthreads();

  float ex[B_];
  #pragma unroll
  for (int b = 0; b < B_; b++) {
    float gm = fmaxf(fmaxf(red[0 * B_ + b], red[1 * B_ + b]),
                     fmaxf(red[2 * B_ + b], red[3 * B_ + b]));
    float e = valid ? __expf(sc[b] - gm) : 0.0f;
    ex[b] = e;
    float es = e;
    #pragma unroll
    for (int off = 32; off > 0; off >>= 1)
      es += __shfl_xor(es, off, 64);
    if (lane == 0) red2[wave * B_ + b] = es;
  }
  __syncthreads();

  #pragma unroll
  for (int b = 0; b < B_; b++) {
    float gs = (red2[0 * B_ + b] + red2[1 * B_ + b]) +
               (red2[2 * B_ + b] + red2[3 * B_ + b]);
    attnW[((size_t)g * B_ + b) * SMX + t] = ex[b] / gs;   // coalesced per-b
  }
}

// ---------------- Kernel 3: weighted value sum + M_img broadcast --------------
// grid = G*4; bid -> g = bid>>2, column chunk cs = bid&3 (widths 128,128,128,64).
// Lane owns float4 of c; half-waves pair s (h = lane>>5 handles s0+2j+h).
// 8 outstanding float4 gathers per thread; no barrier in the main loop.
__global__ __launch_bounds__(256) void out_kernel(
    const float* __restrict__ Zsnd,
    const int*   __restrict__ pad_idx,
    const float* __restrict__ attnW,
    const float* __restrict__ z,
    float*       __restrict__ Mimg,
    float*       __restrict__ Msnd,
    int Smax, int N)
{
  const int bid  = blockIdx.x;
  const int g    = bid >> 2;
  const int cs   = bid & 3;
  const int c0   = cs * 128;
  const int w    = (cs == 3) ? 64 : 128;
  const int t    = threadIdx.x;
  const int lane = t & 63;
  const int wave = t >> 6;
  const int cl   = lane & 31;     // column slot (float4)
  const int h    = lane >> 5;     // s-parity half

  __shared__ int   idxs[SMX];
  __shared__ float attnS[B_ * SMX];   // 16 KB, [b][s]
  __shared__ int   redi[4];

  int myidx = 0, sgv = 0;
  if (t < Smax) {
    int v = pad_idx[(size_t)g * Smax + t];
    bool ok = ((t == 0) || (v != 0)) && (v >= 0) && (v < N);
    myidx = ok ? v : 0;
    sgv   = ok ? (t + 1) : 0;
  }
  idxs[t] = myidx;
  #pragma unroll
  for (int off = 32; off > 0; off >>= 1)
    sgv = max(sgv, __shfl_xor(sgv, off, 64));
  if (lane == 0) redi[wave] = sgv;

  // stage attn [b][s] into LDS (coalesced b128; layout matches attnW)
  #pragma unroll
  for (int i = 0; i < 4; i++) {
    int li = i * 256 + t;
    *(float4*)(attnS + li * 4) = *(const float4*)(attnW + (size_t)g * (B_ * SMX) + li * 4);
  }

  // M_img stripe: Mimg[g, b, c0:c0+w] = z[b, c0:c0+w]
  if (w == 128) {
    #pragma unroll
    for (int i = 0; i < 2; i++) {
      int li = i * 256 + t;
      int b = li >> 5, c4 = li & 31;
      *(float4*)(Mimg + (size_t)g * (B_ * CV) + b * CV + c0 + c4 * 4) =
          *(const float4*)(z + b * C_ + c0 + c4 * 4);
    }
  } else {
    int b = t >> 4, c4 = t & 15;
    *(float4*)(Mimg + (size_t)g * (B_ * CV) + b * CV + c0 + c4 * 4) =
        *(const float4*)(z + b * C_ + c0 + c4 * 4);
  }

  __syncthreads();
  const int sg   = max(max(redi[0], redi[1]), max(redi[2], redi[3]));
  const int sg16 = (sg + 15) & ~15;

  const int b0 = wave * 4;
  const float* vbase = Zsnd + c0 + cl * 4;   // + idx*C_ ; c0+124 <= 508 always in-row
  float4 a0 = make_float4(0.f, 0.f, 0.f, 0.f);
  float4 a1 = make_float4(0.f, 0.f, 0.f, 0.f);
  float4 a2 = make_float4(0.f, 0.f, 0.f, 0.f);
  float4 a3 = make_float4(0.f, 0.f, 0.f, 0.f);

  for (int s0 = 0; s0 < sg16; s0 += 16) {
    float4 v[8];
    #pragma unroll
    for (int j = 0; j < 8; j++) {
      int idx = idxs[s0 + 2 * j + h];
      v[j] = *(const float4*)(vbase + (size_t)idx * C_);
    }
    #pragma unroll
    for (int j = 0; j < 8; j++) {
      int so = s0 + 2 * j + h;
      float w0 = attnS[(b0 + 0) * SMX + so];   // 2 distinct addrs/wave: free
      float w1 = attnS[(b0 + 1) * SMX + so];
      float w2 = attnS[(b0 + 2) * SMX + so];
      float w3 = attnS[(b0 + 3) * SMX + so];
      float4 vv = v[j];
      a0.x += w0 * vv.x; a0.y += w0 * vv.y; a0.z += w0 * vv.z; a0.w += w0 * vv.w;
      a1.x += w1 * vv.x; a1.y += w1 * vv.y; a1.z += w1 * vv.z; a1.w += w1 * vv.w;
      a2.x += w2 * vv.x; a2.y += w2 * vv.y; a2.z += w2 * vv.z; a2.w += w2 * vv.w;
      a3.x += w3 * vv.x; a3.y += w3 * vv.y; a3.z += w3 * vv.z; a3.w += w3 * vv.w;
    }
  }

  // combine s-parity halves: lane cl += lane cl+32
  a0.x += __shfl_xor(a0.x, 32, 64); a0.y += __shfl_xor(a0.y, 32, 64);
  a0.z += __shfl_xor(a0.z, 32, 64); a0.w += __shfl_xor(a0.w, 32, 64);
  a1.x += __shfl_xor(a1.x, 32, 64); a1.y += __shfl_xor(a1.y, 32, 64);
  a1.z += __shfl_xor(a1.z, 32, 64); a1.w += __shfl_xor(a1.w, 32, 64);
  a2.x += __shfl_xor(a2.x, 32, 64); a2.y += __shfl_xor(a2.y, 32, 64);
  a2.z += __shfl_xor(a2.z, 32, 64); a2.w += __shfl_xor(a2.w, 32, 64);
  a3.x += __shfl_xor(a3.x, 32, 64); a3.y += __shfl_xor(a3.y, 32, 64);
  a3.z += __shfl_xor(a3.z, 32, 64); a3.w += __shfl_xor(a3.w, 32, 64);

  if (h == 0 && cl * 4 < w) {
    float* obase = Msnd + (size_t)g * (B_ * CV) + (size_t)b0 * CV + c0 + cl * 4;
    *(float4*)(obase + 0 * CV) = a0;
    *(float4*)(obase + 1 * CV) = a1;
    *(float4*)(obase + 2 * CV) = a2;
    *(float4*)(obase + 3 * CV) = a3;
  }
}

extern "C" void kernel_launch(void* const* d_in, const int* in_sizes, int n_in,
                              void* d_out, int out_size, void* d_ws, size_t ws_size,
                              hipStream_t stream) {
  const float* Zimg   = (const float*)d_in[0];
  const float* Zsnd   = (const float*)d_in[1];
  const int*   padidx = (const int*)d_in[2];
  // d_in[3] = pad_mask (unused; validity derived from pad_idx)
  // d_in[4] = attn_dims (constant 64)

  const int N    = in_sizes[1] / C_;     // rows in Z_snd
  const int Smax = in_sizes[2] / G_;     // padded sequence length (== 256)

  float* z     = (float*)d_ws;                       // B*C fp32
  float* attnW = z + B_ * C_;                        // G*B_*SMX fp32 = 4 MB
  float* Mimg  = (float*)d_out;
  float* Msnd  = Mimg + (size_t)G_ * B_ * CV;

  meanpool_kernel<<<(B_ * C_) / 4, 256, 0, stream>>>(Zimg, z);
  score_kernel<<<G_, 256, 0, stream>>>(Zsnd, padidx, z, attnW, Smax, N);
  out_kernel<<<G_ * 4, 256, 0, stream>>>(Zsnd, padidx, attnW, z, Mimg, Msnd, Smax, N);
}

// Round 4
// 176.291 us; speedup vs baseline: 1.3237x; 1.2323x over previous
//
#include <hip/hip_runtime.h>
#include <math.h>

#define B_  16
#define C_  512
#define A_  64
#define CV  448     // C - A (value / z_img dims)
#define G_  256
#define HW  256
#define SMX 256     // padded S (Smax)
#define BSP 8       // b-rows per score block (2 blocks per group)

// ---------------- Kernel 1: spatial mean pool  z[b,c] = mean(Z_img[b,c,:,:]) ----
__global__ __launch_bounds__(256) void meanpool_kernel(const float* __restrict__ Zimg,
                                                       float* __restrict__ z) {
  int row  = (blockIdx.x << 2) + (threadIdx.x >> 6);   // b*C + c
  int lane = threadIdx.x & 63;
  const float4* p = (const float4*)(Zimg + (size_t)row * HW);
  float4 v = p[lane];
  float s = (v.x + v.y) + (v.z + v.w);
  #pragma unroll
  for (int off = 32; off > 0; off >>= 1)
    s += __shfl_down(s, off, 64);
  if (lane == 0) z[row] = s * (1.0f / HW);
}

// ---------------- Kernel 2: scores + softmax -> attn weights ------------------
// attnW layout: [g][b][s]. Grid = G*2: bid -> g = bid>>1, b0 = (bid&1)*8.
// Anti-spill structure: kv[16] preloaded (16 loads in flight), FMA loop
// #pragma unroll 2 so the scheduler can hoist at most 64 qv floats per body.
__global__ __launch_bounds__(256) void score_kernel(
    const float* __restrict__ Zsnd,
    const int*   __restrict__ pad_idx,
    const float* __restrict__ z,
    float*       __restrict__ attnW,
    int Smax, int N)
{
  const int bid  = blockIdx.x;
  const int g    = bid >> 1;
  const int b0   = (bid & 1) * BSP;
  const int t    = threadIdx.x;
  const int lane = t & 63;
  const int wave = t >> 6;

  __shared__ float qs[BSP * A_];      // 2 KB
  __shared__ float red[4 * BSP];
  __shared__ float red2[4 * BSP];

  // validity from pad_idx (valid <=> j==0 || idx!=0; prefix-contiguous)
  int myidx = -1;
  if (t < Smax) {
    int v = pad_idx[(size_t)g * Smax + t];
    bool ok = ((t == 0) || (v != 0)) && (v >= 0) && (v < N);
    myidx = ok ? v : -1;
  }
  const bool valid = (myidx >= 0);

  if (t < BSP * 16) {                 // 8 b x 16 a4 = 128 float4s
    int b = t >> 4, a4 = t & 15;
    *(float4*)(qs + b * A_ + a4 * 4) =
        *(const float4*)(z + (b0 + b) * C_ + CV + a4 * 4);
  }
  __syncthreads();

  // preload full key row: 16 float4 loads in flight
  const float* krow = Zsnd + (size_t)(valid ? myidx : 0) * C_ + CV;
  float4 kv[16];
  #pragma unroll
  for (int a4 = 0; a4 < 16; a4++)
    kv[a4] = *(const float4*)(krow + a4 * 4);

  float sc[BSP];
  #pragma unroll
  for (int b = 0; b < BSP; b++) sc[b] = 0.0f;

  #pragma unroll 2
  for (int a4 = 0; a4 < 16; a4++) {
    #pragma unroll
    for (int b = 0; b < BSP; b++) {
      float4 qv = *(const float4*)(qs + b * A_ + a4 * 4);  // wave-uniform broadcast
      sc[b] += qv.x * kv[a4].x + qv.y * kv[a4].y +
               qv.z * kv[a4].z + qv.w * kv[a4].w;
    }
  }

  // softmax over s (threads): butterfly + cross-wave LDS combine
  #pragma unroll
  for (int b = 0; b < BSP; b++) {
    float v = valid ? sc[b] : -INFINITY;
    #pragma unroll
    for (int off = 32; off > 0; off >>= 1)
      v = fmaxf(v, __shfl_xor(v, off, 64));
    if (lane == 0) red[wave * BSP + b] = v;
  }
  __syncthreads();

  float ex[BSP];
  #pragma unroll
  for (int b = 0; b < BSP; b++) {
    float gm = fmaxf(fmaxf(red[0 * BSP + b], red[1 * BSP + b]),
                     fmaxf(red[2 * BSP + b], red[3 * BSP + b]));
    float e = valid ? __expf(sc[b] - gm) : 0.0f;
    ex[b] = e;
    float es = e;
    #pragma unroll
    for (int off = 32; off > 0; off >>= 1)
      es += __shfl_xor(es, off, 64);
    if (lane == 0) red2[wave * BSP + b] = es;
  }
  __syncthreads();

  #pragma unroll
  for (int b = 0; b < BSP; b++) {
    float gs = (red2[0 * BSP + b] + red2[1 * BSP + b]) +
               (red2[2 * BSP + b] + red2[3 * BSP + b]);
    attnW[((size_t)g * B_ + b0 + b) * SMX + t] = ex[b] / gs;   // coalesced per-b
  }
}

// ---------------- Kernel 3: weighted value sum + M_img broadcast --------------
// grid = G*4; bid -> g = bid>>2, column chunk cs = bid&3 (widths 128,128,128,64).
// Lane owns float4 of c; half-waves pair s (h = lane>>5 handles s0+2j+h).
// 8 outstanding float4 gathers per thread; no barrier in the main loop.
__global__ __launch_bounds__(256) void out_kernel(
    const float* __restrict__ Zsnd,
    const int*   __restrict__ pad_idx,
    const float* __restrict__ attnW,
    const float* __restrict__ z,
    float*       __restrict__ Mimg,
    float*       __restrict__ Msnd,
    int Smax, int N)
{
  const int bid  = blockIdx.x;
  const int g    = bid >> 2;
  const int cs   = bid & 3;
  const int c0   = cs * 128;
  const int w    = (cs == 3) ? 64 : 128;
  const int t    = threadIdx.x;
  const int lane = t & 63;
  const int wave = t >> 6;
  const int cl   = lane & 31;     // column slot (float4)
  const int h    = lane >> 5;     // s-parity half

  __shared__ int   idxs[SMX];
  __shared__ float attnS[B_ * SMX];   // 16 KB, [b][s]
  __shared__ int   redi[4];

  int myidx = 0, sgv = 0;
  if (t < Smax) {
    int v = pad_idx[(size_t)g * Smax + t];
    bool ok = ((t == 0) || (v != 0)) && (v >= 0) && (v < N);
    myidx = ok ? v : 0;
    sgv   = ok ? (t + 1) : 0;
  }
  idxs[t] = myidx;
  #pragma unroll
  for (int off = 32; off > 0; off >>= 1)
    sgv = max(sgv, __shfl_xor(sgv, off, 64));
  if (lane == 0) redi[wave] = sgv;

  // stage attn [b][s] into LDS (coalesced b128; layout matches attnW)
  #pragma unroll
  for (int i = 0; i < 4; i++) {
    int li = i * 256 + t;
    *(float4*)(attnS + li * 4) = *(const float4*)(attnW + (size_t)g * (B_ * SMX) + li * 4);
  }

  // M_img stripe: Mimg[g, b, c0:c0+w] = z[b, c0:c0+w]
  if (w == 128) {
    #pragma unroll
    for (int i = 0; i < 2; i++) {
      int li = i * 256 + t;
      int b = li >> 5, c4 = li & 31;
      *(float4*)(Mimg + (size_t)g * (B_ * CV) + b * CV + c0 + c4 * 4) =
          *(const float4*)(z + b * C_ + c0 + c4 * 4);
    }
  } else {
    int b = t >> 4, c4 = t & 15;
    *(float4*)(Mimg + (size_t)g * (B_ * CV) + b * CV + c0 + c4 * 4) =
        *(const float4*)(z + b * C_ + c0 + c4 * 4);
  }

  __syncthreads();
  const int sg   = max(max(redi[0], redi[1]), max(redi[2], redi[3]));
  const int sg16 = (sg + 15) & ~15;

  const int b0 = wave * 4;
  const float* vbase = Zsnd + c0 + cl * 4;   // + idx*C_ ; c0+124 <= 508 always in-row
  float4 a0 = make_float4(0.f, 0.f, 0.f, 0.f);
  float4 a1 = make_float4(0.f, 0.f, 0.f, 0.f);
  float4 a2 = make_float4(0.f, 0.f, 0.f, 0.f);
  float4 a3 = make_float4(0.f, 0.f, 0.f, 0.f);

  for (int s0 = 0; s0 < sg16; s0 += 16) {
    float4 v[8];
    #pragma unroll
    for (int j = 0; j < 8; j++) {
      int idx = idxs[s0 + 2 * j + h];
      v[j] = *(const float4*)(vbase + (size_t)idx * C_);
    }
    #pragma unroll
    for (int j = 0; j < 8; j++) {
      int so = s0 + 2 * j + h;
      float w0 = attnS[(b0 + 0) * SMX + so];   // 2 distinct addrs/wave: free
      float w1 = attnS[(b0 + 1) * SMX + so];
      float w2 = attnS[(b0 + 2) * SMX + so];
      float w3 = attnS[(b0 + 3) * SMX + so];
      float4 vv = v[j];
      a0.x += w0 * vv.x; a0.y += w0 * vv.y; a0.z += w0 * vv.z; a0.w += w0 * vv.w;
      a1.x += w1 * vv.x; a1.y += w1 * vv.y; a1.z += w1 * vv.z; a1.w += w1 * vv.w;
      a2.x += w2 * vv.x; a2.y += w2 * vv.y; a2.z += w2 * vv.z; a2.w += w2 * vv.w;
      a3.x += w3 * vv.x; a3.y += w3 * vv.y; a3.z += w3 * vv.z; a3.w += w3 * vv.w;
    }
  }

  // combine s-parity halves: lane cl += lane cl+32
  a0.x += __shfl_xor(a0.x, 32, 64); a0.y += __shfl_xor(a0.y, 32, 64);
  a0.z += __shfl_xor(a0.z, 32, 64); a0.w += __shfl_xor(a0.w, 32, 64);
  a1.x += __shfl_xor(a1.x, 32, 64); a1.y += __shfl_xor(a1.y, 32, 64);
  a1.z += __shfl_xor(a1.z, 32, 64); a1.w += __shfl_xor(a1.w, 32, 64);
  a2.x += __shfl_xor(a2.x, 32, 64); a2.y += __shfl_xor(a2.y, 32, 64);
  a2.z += __shfl_xor(a2.z, 32, 64); a2.w += __shfl_xor(a2.w, 32, 64);
  a3.x += __shfl_xor(a3.x, 32, 64); a3.y += __shfl_xor(a3.y, 32, 64);
  a3.z += __shfl_xor(a3.z, 32, 64); a3.w += __shfl_xor(a3.w, 32, 64);

  if (h == 0 && cl * 4 < w) {
    float* obase = Msnd + (size_t)g * (B_ * CV) + (size_t)b0 * CV + c0 + cl * 4;
    *(float4*)(obase + 0 * CV) = a0;
    *(float4*)(obase + 1 * CV) = a1;
    *(float4*)(obase + 2 * CV) = a2;
    *(float4*)(obase + 3 * CV) = a3;
  }
}

extern "C" void kernel_launch(void* const* d_in, const int* in_sizes, int n_in,
                              void* d_out, int out_size, void* d_ws, size_t ws_size,
                              hipStream_t stream) {
  const float* Zimg   = (const float*)d_in[0];
  const float* Zsnd   = (const float*)d_in[1];
  const int*   padidx = (const int*)d_in[2];
  // d_in[3] = pad_mask (unused; validity derived from pad_idx)
  // d_in[4] = attn_dims (constant 64)

  const int N    = in_sizes[1] / C_;     // rows in Z_snd
  const int Smax = in_sizes[2] / G_;     // padded sequence length (== 256)

  float* z     = (float*)d_ws;                       // B*C fp32
  float* attnW = z + B_ * C_;                        // G*B_*SMX fp32 = 4 MB
  float* Mimg  = (float*)d_out;
  float* Msnd  = Mimg + (size_t)G_ * B_ * CV;

  meanpool_kernel<<<(B_ * C_) / 4, 256, 0, stream>>>(Zimg, z);
  score_kernel<<<G_ * 2, 256, 0, stream>>>(Zsnd, padidx, z, attnW, Smax, N);
  out_kernel<<<G_ * 4, 256, 0, stream>>>(Zsnd, padidx, attnW, z, Mimg, Msnd, Smax, N);
}

// Round 5
// 160.483 us; speedup vs baseline: 1.4540x; 1.0985x over previous
//
#include <hip/hip_runtime.h>
#include <math.h>

#define B_  16
#define C_  512
#define A_  64
#define CV  448     // C - A (value / z_img dims)
#define G_  256
#define HW  256
#define SMX 256     // padded S (Smax)
#define BSP 8       // b-rows per score block (2 blocks per group)

// ---------------- Kernel 1: spatial mean pool  z[b,c] = mean(Z_img[b,c,:,:]) ----
__global__ __launch_bounds__(256) void meanpool_kernel(const float* __restrict__ Zimg,
                                                       float* __restrict__ z) {
  int row  = (blockIdx.x << 2) + (threadIdx.x >> 6);   // b*C + c
  int lane = threadIdx.x & 63;
  const float4* p = (const float4*)(Zimg + (size_t)row * HW);
  float4 v = p[lane];
  float s = (v.x + v.y) + (v.z + v.w);
  #pragma unroll
  for (int off = 32; off > 0; off >>= 1)
    s += __shfl_down(s, off, 64);
  if (lane == 0) z[row] = s * (1.0f / HW);
}

// ---------------- Kernel 2: scores + softmax -> attn weights ------------------
// attnW layout: [g][s][b] (16 floats per s). Grid = G*2: g = bid>>1, b0 = (bid&1)*8.
// Anti-spill: K-dot in 4 chunks of 4 float4 loads; sched_barrier(0) between
// chunks caps live values (~50 regs) so the scheduler cannot create a spill.
__global__ __launch_bounds__(256) void score_kernel(
    const float* __restrict__ Zsnd,
    const int*   __restrict__ pad_idx,
    const float* __restrict__ z,
    float*       __restrict__ attnW,
    int Smax, int N)
{
  const int bid  = blockIdx.x;
  const int g    = bid >> 1;
  const int b0   = (bid & 1) * BSP;
  const int t    = threadIdx.x;
  const int lane = t & 63;
  const int wave = t >> 6;

  __shared__ float qs[BSP * A_];      // 2 KB
  __shared__ float red[4 * BSP];
  __shared__ float red2[4 * BSP];

  // validity from pad_idx (valid <=> j==0 || idx!=0; prefix-contiguous)
  int myidx = -1;
  if (t < Smax) {
    int v = pad_idx[(size_t)g * Smax + t];
    bool ok = ((t == 0) || (v != 0)) && (v >= 0) && (v < N);
    myidx = ok ? v : -1;
  }
  const bool valid = (myidx >= 0);

  if (t < BSP * 16) {                 // 8 b x 16 a4 = 128 float4s
    int b = t >> 4, a4 = t & 15;
    *(float4*)(qs + b * A_ + a4 * 4) =
        *(const float4*)(z + (b0 + b) * C_ + CV + a4 * 4);
  }
  __syncthreads();

  const float* krow = Zsnd + (size_t)(valid ? myidx : 0) * C_ + CV;
  float sc[BSP];
  #pragma unroll
  for (int b = 0; b < BSP; b++) sc[b] = 0.0f;

  #pragma unroll
  for (int c = 0; c < 4; c++) {
    float4 k0 = *(const float4*)(krow + c * 16 + 0);
    float4 k1 = *(const float4*)(krow + c * 16 + 4);
    float4 k2 = *(const float4*)(krow + c * 16 + 8);
    float4 k3 = *(const float4*)(krow + c * 16 + 12);
    #pragma unroll
    for (int b = 0; b < BSP; b++) {
      const float* qb = qs + b * A_ + c * 16;
      float4 q0 = *(const float4*)(qb + 0);
      float4 q1 = *(const float4*)(qb + 4);
      float4 q2 = *(const float4*)(qb + 8);
      float4 q3 = *(const float4*)(qb + 12);
      sc[b] += q0.x * k0.x + q0.y * k0.y + q0.z * k0.z + q0.w * k0.w
             + q1.x * k1.x + q1.y * k1.y + q1.z * k1.z + q1.w * k1.w
             + q2.x * k2.x + q2.y * k2.y + q2.z * k2.z + q2.w * k2.w
             + q3.x * k3.x + q3.y * k3.y + q3.z * k3.z + q3.w * k3.w;
    }
    __builtin_amdgcn_sched_barrier(0);   // cap cross-chunk hoisting (anti-spill)
  }

  // softmax over s (threads): butterfly + cross-wave LDS combine
  #pragma unroll
  for (int b = 0; b < BSP; b++) {
    float v = valid ? sc[b] : -INFINITY;
    #pragma unroll
    for (int off = 32; off > 0; off >>= 1)
      v = fmaxf(v, __shfl_xor(v, off, 64));
    if (lane == 0) red[wave * BSP + b] = v;
  }
  __syncthreads();

  float ex[BSP];
  #pragma unroll
  for (int b = 0; b < BSP; b++) {
    float gm = fmaxf(fmaxf(red[0 * BSP + b], red[1 * BSP + b]),
                     fmaxf(red[2 * BSP + b], red[3 * BSP + b]));
    float e = valid ? __expf(sc[b] - gm) : 0.0f;
    ex[b] = e;
    float es = e;
    #pragma unroll
    for (int off = 32; off > 0; off >>= 1)
      es += __shfl_xor(es, off, 64);
    if (lane == 0) red2[wave * BSP + b] = es;
  }
  __syncthreads();

  float* orow = attnW + ((size_t)g * SMX + t) * B_ + b0;
  float4 o0, o1;
  {
    float iv[BSP];
    #pragma unroll
    for (int b = 0; b < BSP; b++) {
      float gs = (red2[0 * BSP + b] + red2[1 * BSP + b]) +
                 (red2[2 * BSP + b] + red2[3 * BSP + b]);
      iv[b] = ex[b] / gs;
    }
    o0 = make_float4(iv[0], iv[1], iv[2], iv[3]);
    o1 = make_float4(iv[4], iv[5], iv[6], iv[7]);
  }
  *(float4*)(orow + 0) = o0;
  *(float4*)(orow + 4) = o1;
}

// ---------------- Kernel 3: weighted value sum + M_img broadcast --------------
// grid = G*4; bid -> g = bid>>2, column chunk cs (widths 128,128,128,64).
// 2x2 wave split: bh = wave&1 picks 8 b-rows, sh = wave>>1 picks s-subset
// (halves duplicate value loads). Lane: cl = float4 column slot, h = s parity.
// attnT is [s][b] so attn reads are 2 b128 LDS broadcasts per stripe.
__global__ __launch_bounds__(256) void out_kernel(
    const float* __restrict__ Zsnd,
    const int*   __restrict__ pad_idx,
    const float* __restrict__ attnW,
    const float* __restrict__ z,
    float*       __restrict__ Mimg,
    float*       __restrict__ Msnd,
    int Smax, int N)
{
  const int bid  = blockIdx.x;
  const int g    = bid >> 2;
  const int cs   = bid & 3;
  const int c0   = cs * 128;
  const int w    = (cs == 3) ? 64 : 128;
  const int t    = threadIdx.x;
  const int lane = t & 63;
  const int wave = t >> 6;
  const int cl   = lane & 31;     // float4 column slot
  const int h    = lane >> 5;     // s parity within subset
  const int bh   = wave & 1;      // b half
  const int sh   = wave >> 1;     // s subset
  const int b0   = bh * 8;

  __shared__ float attnT[SMX * B_];   // 16 KB, [s][b]; reused as redS after loop
  __shared__ int   idxs[SMX];
  __shared__ int   redi[4];

  int myidx = 0, sgv = 0;
  if (t < Smax) {
    int v = pad_idx[(size_t)g * Smax + t];
    bool ok = ((t == 0) || (v != 0)) && (v >= 0) && (v < N);
    myidx = ok ? v : 0;
    sgv   = ok ? (t + 1) : 0;
  }
  idxs[t] = myidx;
  #pragma unroll
  for (int off = 32; off > 0; off >>= 1)
    sgv = max(sgv, __shfl_xor(sgv, off, 64));
  if (lane == 0) redi[wave] = sgv;

  // stage attn [s][b] into LDS (same bytes as attnW row; coalesced b128)
  #pragma unroll
  for (int i = 0; i < 4; i++) {
    int li = i * 256 + t;
    *(float4*)(attnT + li * 4) = *(const float4*)(attnW + (size_t)g * (SMX * B_) + li * 4);
  }

  // M_img stripe: Mimg[g, b, c0:c0+w] = z[b, c0:c0+w]
  if (w == 128) {
    #pragma unroll
    for (int i = 0; i < 2; i++) {
      int li = i * 256 + t;
      int b = li >> 5, c4 = li & 31;
      *(float4*)(Mimg + (size_t)g * (B_ * CV) + b * CV + c0 + c4 * 4) =
          *(const float4*)(z + b * C_ + c0 + c4 * 4);
    }
  } else {
    int b = t >> 4, c4 = t & 15;
    *(float4*)(Mimg + (size_t)g * (B_ * CV) + b * CV + c0 + c4 * 4) =
        *(const float4*)(z + b * C_ + c0 + c4 * 4);
  }

  __syncthreads();
  const int sg   = max(max(redi[0], redi[1]), max(redi[2], redi[3]));
  const int sg16 = (sg + 15) & ~15;

  const float* vbase = Zsnd + c0 + cl * 4;   // + idx*C_ ; col <= 511 always in-row
  float4 acc[8];
  #pragma unroll
  for (int b = 0; b < 8; b++) acc[b] = make_float4(0.f, 0.f, 0.f, 0.f);

  for (int s0 = 0; s0 < sg16; s0 += 16) {
    float4 v[4];
    int so[4];
    #pragma unroll
    for (int j = 0; j < 4; j++) {
      so[j] = s0 + 4 * j + 2 * sh + h;
      int idx = idxs[so[j]];
      v[j] = *(const float4*)(vbase + (size_t)idx * C_);
    }
    #pragma unroll
    for (int j = 0; j < 4; j++) {
      float4 w0 = *(const float4*)(attnT + so[j] * B_ + b0);      // b0..b0+3
      float4 w1 = *(const float4*)(attnT + so[j] * B_ + b0 + 4);  // b0+4..b0+7
      float4 vv = v[j];
      acc[0].x += w0.x * vv.x; acc[0].y += w0.x * vv.y; acc[0].z += w0.x * vv.z; acc[0].w += w0.x * vv.w;
      acc[1].x += w0.y * vv.x; acc[1].y += w0.y * vv.y; acc[1].z += w0.y * vv.z; acc[1].w += w0.y * vv.w;
      acc[2].x += w0.z * vv.x; acc[2].y += w0.z * vv.y; acc[2].z += w0.z * vv.z; acc[2].w += w0.z * vv.w;
      acc[3].x += w0.w * vv.x; acc[3].y += w0.w * vv.y; acc[3].z += w0.w * vv.z; acc[3].w += w0.w * vv.w;
      acc[4].x += w1.x * vv.x; acc[4].y += w1.x * vv.y; acc[4].z += w1.x * vv.z; acc[4].w += w1.x * vv.w;
      acc[5].x += w1.y * vv.x; acc[5].y += w1.y * vv.y; acc[5].z += w1.y * vv.z; acc[5].w += w1.y * vv.w;
      acc[6].x += w1.z * vv.x; acc[6].y += w1.z * vv.y; acc[6].z += w1.z * vv.z; acc[6].w += w1.z * vv.w;
      acc[7].x += w1.w * vv.x; acc[7].y += w1.w * vv.y; acc[7].z += w1.w * vv.z; acc[7].w += w1.w * vv.w;
    }
  }

  // ---- cross-wave combine: sh==1 partials -> LDS (reuse attnT), sh==0 adds ----
  __syncthreads();                      // everyone done reading attnT
  float* redS = attnT;                  // [bh][b][lane] float4 = 2*8*64*4 floats = 16 KB
  if (sh == 1) {
    #pragma unroll
    for (int b = 0; b < 8; b++)
      *(float4*)(redS + (((size_t)bh * 8 + b) * 64 + lane) * 4) = acc[b];
  }
  __syncthreads();
  if (sh == 0) {
    #pragma unroll
    for (int b = 0; b < 8; b++) {
      float4 o = *(const float4*)(redS + (((size_t)bh * 8 + b) * 64 + lane) * 4);
      acc[b].x += o.x; acc[b].y += o.y; acc[b].z += o.z; acc[b].w += o.w;
      acc[b].x += __shfl_xor(acc[b].x, 32, 64);
      acc[b].y += __shfl_xor(acc[b].y, 32, 64);
      acc[b].z += __shfl_xor(acc[b].z, 32, 64);
      acc[b].w += __shfl_xor(acc[b].w, 32, 64);
    }
    if (h == 0 && cl * 4 < w) {
      float* obase = Msnd + (size_t)g * (B_ * CV) + (size_t)b0 * CV + c0 + cl * 4;
      #pragma unroll
      for (int b = 0; b < 8; b++)
        *(float4*)(obase + b * CV) = acc[b];
    }
  }
}

extern "C" void kernel_launch(void* const* d_in, const int* in_sizes, int n_in,
                              void* d_out, int out_size, void* d_ws, size_t ws_size,
                              hipStream_t stream) {
  const float* Zimg   = (const float*)d_in[0];
  const float* Zsnd   = (const float*)d_in[1];
  const int*   padidx = (const int*)d_in[2];
  // d_in[3] = pad_mask (unused; validity derived from pad_idx)
  // d_in[4] = attn_dims (constant 64)

  const int N    = in_sizes[1] / C_;     // rows in Z_snd
  const int Smax = in_sizes[2] / G_;     // padded sequence length (== 256)

  float* z     = (float*)d_ws;                       // B*C fp32
  float* attnW = z + B_ * C_;                        // G*SMX*B_ fp32 = 4 MB
  float* Mimg  = (float*)d_out;
  float* Msnd  = Mimg + (size_t)G_ * B_ * CV;

  meanpool_kernel<<<(B_ * C_) / 4, 256, 0, stream>>>(Zimg, z);
  score_kernel<<<G_ * 2, 256, 0, stream>>>(Zsnd, padidx, z, attnW, Smax, N);
  out_kernel<<<G_ * 4, 256, 0, stream>>>(Zsnd, padidx, attnW, z, Mimg, Msnd, Smax, N);
}

// Round 6
// 159.945 us; speedup vs baseline: 1.4589x; 1.0034x over previous
//
#include <hip/hip_runtime.h>
#include <math.h>

#define B_  16
#define C_  512
#define A_  64
#define CV  448     // C - A (value / z_img dims)
#define G_  256
#define HW  256
#define SMX 256     // padded S (Smax)
#define BSP 8       // b-rows per score block (2 blocks per group)

// ---------------- Kernel 1: spatial mean pool  z[b,c] = mean(Z_img[b,c,:,:]) ----
__global__ __launch_bounds__(256) void meanpool_kernel(const float* __restrict__ Zimg,
                                                       float* __restrict__ z) {
  int row  = (blockIdx.x << 2) + (threadIdx.x >> 6);   // b*C + c
  int lane = threadIdx.x & 63;
  const float4* p = (const float4*)(Zimg + (size_t)row * HW);
  float4 v = p[lane];
  float s = (v.x + v.y) + (v.z + v.w);
  #pragma unroll
  for (int off = 32; off > 0; off >>= 1)
    s += __shfl_down(s, off, 64);
  if (lane == 0) z[row] = s * (1.0f / HW);
}

// ---------------- Kernel 2: scores + softmax -> attn weights ------------------
// attnW layout: [g][s][b] (16 floats per s). Grid = G*2.
// XCD swizzle: g = bid&255, b0 = (bid>>8)*8 — both b-half blocks of a group
// are bid and bid+256 (same bid%8 => same XCD) so the shared key-row fetch
// is deduped in that XCD's L2.
// Anti-spill: K-dot in 4 chunks of 4 float4 loads; sched_barrier(0) between
// chunks caps live values (~50 regs) so the scheduler cannot create a spill.
__global__ __launch_bounds__(256) void score_kernel(
    const float* __restrict__ Zsnd,
    const int*   __restrict__ pad_idx,
    const float* __restrict__ z,
    float*       __restrict__ attnW,
    int Smax, int N)
{
  const int bid  = blockIdx.x;
  const int g    = bid & 255;
  const int b0   = (bid >> 8) * BSP;
  const int t    = threadIdx.x;
  const int lane = t & 63;
  const int wave = t >> 6;

  __shared__ float qs[BSP * A_];      // 2 KB
  __shared__ float red[4 * BSP];
  __shared__ float red2[4 * BSP];

  // validity from pad_idx (valid <=> j==0 || idx!=0; prefix-contiguous)
  int myidx = -1;
  if (t < Smax) {
    int v = pad_idx[(size_t)g * Smax + t];
    bool ok = ((t == 0) || (v != 0)) && (v >= 0) && (v < N);
    myidx = ok ? v : -1;
  }
  const bool valid = (myidx >= 0);

  if (t < BSP * 16) {                 // 8 b x 16 a4 = 128 float4s
    int b = t >> 4, a4 = t & 15;
    *(float4*)(qs + b * A_ + a4 * 4) =
        *(const float4*)(z + (b0 + b) * C_ + CV + a4 * 4);
  }
  __syncthreads();

  const float* krow = Zsnd + (size_t)(valid ? myidx : 0) * C_ + CV;
  float sc[BSP];
  #pragma unroll
  for (int b = 0; b < BSP; b++) sc[b] = 0.0f;

  #pragma unroll
  for (int c = 0; c < 4; c++) {
    float4 k0 = *(const float4*)(krow + c * 16 + 0);
    float4 k1 = *(const float4*)(krow + c * 16 + 4);
    float4 k2 = *(const float4*)(krow + c * 16 + 8);
    float4 k3 = *(const float4*)(krow + c * 16 + 12);
    #pragma unroll
    for (int b = 0; b < BSP; b++) {
      const float* qb = qs + b * A_ + c * 16;
      float4 q0 = *(const float4*)(qb + 0);
      float4 q1 = *(const float4*)(qb + 4);
      float4 q2 = *(const float4*)(qb + 8);
      float4 q3 = *(const float4*)(qb + 12);
      sc[b] += q0.x * k0.x + q0.y * k0.y + q0.z * k0.z + q0.w * k0.w
             + q1.x * k1.x + q1.y * k1.y + q1.z * k1.z + q1.w * k1.w
             + q2.x * k2.x + q2.y * k2.y + q2.z * k2.z + q2.w * k2.w
             + q3.x * k3.x + q3.y * k3.y + q3.z * k3.z + q3.w * k3.w;
    }
    __builtin_amdgcn_sched_barrier(0);   // cap cross-chunk hoisting (anti-spill)
  }

  // softmax over s (threads): butterfly + cross-wave LDS combine
  #pragma unroll
  for (int b = 0; b < BSP; b++) {
    float v = valid ? sc[b] : -INFINITY;
    #pragma unroll
    for (int off = 32; off > 0; off >>= 1)
      v = fmaxf(v, __shfl_xor(v, off, 64));
    if (lane == 0) red[wave * BSP + b] = v;
  }
  __syncthreads();

  float ex[BSP];
  #pragma unroll
  for (int b = 0; b < BSP; b++) {
    float gm = fmaxf(fmaxf(red[0 * BSP + b], red[1 * BSP + b]),
                     fmaxf(red[2 * BSP + b], red[3 * BSP + b]));
    float e = valid ? __expf(sc[b] - gm) : 0.0f;
    ex[b] = e;
    float es = e;
    #pragma unroll
    for (int off = 32; off > 0; off >>= 1)
      es += __shfl_xor(es, off, 64);
    if (lane == 0) red2[wave * BSP + b] = es;
  }
  __syncthreads();

  float* orow = attnW + ((size_t)g * SMX + t) * B_ + b0;
  float4 o0, o1;
  {
    float iv[BSP];
    #pragma unroll
    for (int b = 0; b < BSP; b++) {
      float gs = (red2[0 * BSP + b] + red2[1 * BSP + b]) +
                 (red2[2 * BSP + b] + red2[3 * BSP + b]);
      iv[b] = ex[b] / gs;
    }
    o0 = make_float4(iv[0], iv[1], iv[2], iv[3]);
    o1 = make_float4(iv[4], iv[5], iv[6], iv[7]);
  }
  *(float4*)(orow + 0) = o0;
  *(float4*)(orow + 4) = o1;
}

// ---------------- Kernel 3: weighted value sum + M_img broadcast --------------
// grid = G*4. XCD swizzle: g = bid&255, chunk cs = bid>>8 — the 4 chunk blocks
// of a group share bid%8 (same XCD) so the 16 KB attn stage is L2-deduped.
// 2x2 wave split: bh = wave&1 picks 8 b-rows, sh = wave>>1 picks s-subset.
// Lane: cl = float4 column slot, h = s parity. 8 outstanding gathers/thread.
__global__ __launch_bounds__(256) void out_kernel(
    const float* __restrict__ Zsnd,
    const int*   __restrict__ pad_idx,
    const float* __restrict__ attnW,
    const float* __restrict__ z,
    float*       __restrict__ Mimg,
    float*       __restrict__ Msnd,
    int Smax, int N)
{
  const int bid  = blockIdx.x;
  const int g    = bid & 255;
  const int cs   = bid >> 8;
  const int c0   = cs * 128;
  const int w    = (cs == 3) ? 64 : 128;
  const int t    = threadIdx.x;
  const int lane = t & 63;
  const int wave = t >> 6;
  const int cl   = lane & 31;     // float4 column slot
  const int h    = lane >> 5;     // s parity within subset
  const int bh   = wave & 1;      // b half
  const int sh   = wave >> 1;     // s subset
  const int b0   = bh * 8;

  __shared__ float attnT[SMX * B_];   // 16 KB, [s][b]; reused as redS after loop
  __shared__ int   idxs[SMX];
  __shared__ int   redi[4];

  int myidx = 0, sgv = 0;
  if (t < Smax) {
    int v = pad_idx[(size_t)g * Smax + t];
    bool ok = ((t == 0) || (v != 0)) && (v >= 0) && (v < N);
    myidx = ok ? v : 0;
    sgv   = ok ? (t + 1) : 0;
  }
  idxs[t] = myidx;
  #pragma unroll
  for (int off = 32; off > 0; off >>= 1)
    sgv = max(sgv, __shfl_xor(sgv, off, 64));
  if (lane == 0) redi[wave] = sgv;

  // stage attn [s][b] into LDS (same bytes as attnW row; coalesced b128)
  #pragma unroll
  for (int i = 0; i < 4; i++) {
    int li = i * 256 + t;
    *(float4*)(attnT + li * 4) = *(const float4*)(attnW + (size_t)g * (SMX * B_) + li * 4);
  }

  // M_img stripe: Mimg[g, b, c0:c0+w] = z[b, c0:c0+w]
  if (w == 128) {
    #pragma unroll
    for (int i = 0; i < 2; i++) {
      int li = i * 256 + t;
      int b = li >> 5, c4 = li & 31;
      *(float4*)(Mimg + (size_t)g * (B_ * CV) + b * CV + c0 + c4 * 4) =
          *(const float4*)(z + b * C_ + c0 + c4 * 4);
    }
  } else {
    int b = t >> 4, c4 = t & 15;
    *(float4*)(Mimg + (size_t)g * (B_ * CV) + b * CV + c0 + c4 * 4) =
        *(const float4*)(z + b * C_ + c0 + c4 * 4);
  }

  __syncthreads();
  const int sg   = max(max(redi[0], redi[1]), max(redi[2], redi[3]));
  const int sg32 = (sg + 31) & ~31;

  const float* vbase = Zsnd + c0 + cl * 4;   // + idx*C_ ; col <= 511 always in-row
  float4 acc[8];
  #pragma unroll
  for (int b = 0; b < 8; b++) acc[b] = make_float4(0.f, 0.f, 0.f, 0.f);

  for (int s0 = 0; s0 < sg32; s0 += 32) {
    float4 v[8];
    int so[8];
    #pragma unroll
    for (int j = 0; j < 8; j++) {
      so[j] = s0 + 4 * j + 2 * sh + h;
      int idx = idxs[so[j]];
      v[j] = *(const float4*)(vbase + (size_t)idx * C_);
    }
    #pragma unroll
    for (int j = 0; j < 8; j++) {
      float4 w0 = *(const float4*)(attnT + so[j] * B_ + b0);      // b0..b0+3
      float4 w1 = *(const float4*)(attnT + so[j] * B_ + b0 + 4);  // b0+4..b0+7
      float4 vv = v[j];
      acc[0].x += w0.x * vv.x; acc[0].y += w0.x * vv.y; acc[0].z += w0.x * vv.z; acc[0].w += w0.x * vv.w;
      acc[1].x += w0.y * vv.x; acc[1].y += w0.y * vv.y; acc[1].z += w0.y * vv.z; acc[1].w += w0.y * vv.w;
      acc[2].x += w0.z * vv.x; acc[2].y += w0.z * vv.y; acc[2].z += w0.z * vv.z; acc[2].w += w0.z * vv.w;
      acc[3].x += w0.w * vv.x; acc[3].y += w0.w * vv.y; acc[3].z += w0.w * vv.z; acc[3].w += w0.w * vv.w;
      acc[4].x += w1.x * vv.x; acc[4].y += w1.x * vv.y; acc[4].z += w1.x * vv.z; acc[4].w += w1.x * vv.w;
      acc[5].x += w1.y * vv.x; acc[5].y += w1.y * vv.y; acc[5].z += w1.y * vv.z; acc[5].w += w1.y * vv.w;
      acc[6].x += w1.z * vv.x; acc[6].y += w1.z * vv.y; acc[6].z += w1.z * vv.z; acc[6].w += w1.z * vv.w;
      acc[7].x += w1.w * vv.x; acc[7].y += w1.w * vv.y; acc[7].z += w1.w * vv.z; acc[7].w += w1.w * vv.w;
    }
  }

  // ---- cross-wave combine: sh==1 partials -> LDS (reuse attnT), sh==0 adds ----
  __syncthreads();                      // everyone done reading attnT
  float* redS = attnT;                  // [bh][b][lane] float4 = 2*8*64*4 floats = 16 KB
  if (sh == 1) {
    #pragma unroll
    for (int b = 0; b < 8; b++)
      *(float4*)(redS + (((size_t)bh * 8 + b) * 64 + lane) * 4) = acc[b];
  }
  __syncthreads();
  if (sh == 0) {
    #pragma unroll
    for (int b = 0; b < 8; b++) {
      float4 o = *(const float4*)(redS + (((size_t)bh * 8 + b) * 64 + lane) * 4);
      acc[b].x += o.x; acc[b].y += o.y; acc[b].z += o.z; acc[b].w += o.w;
      acc[b].x += __shfl_xor(acc[b].x, 32, 64);
      acc[b].y += __shfl_xor(acc[b].y, 32, 64);
      acc[b].z += __shfl_xor(acc[b].z, 32, 64);
      acc[b].w += __shfl_xor(acc[b].w, 32, 64);
    }
    if (h == 0 && cl * 4 < w) {
      float* obase = Msnd + (size_t)g * (B_ * CV) + (size_t)b0 * CV + c0 + cl * 4;
      #pragma unroll
      for (int b = 0; b < 8; b++)
        *(float4*)(obase + b * CV) = acc[b];
    }
  }
}

extern "C" void kernel_launch(void* const* d_in, const int* in_sizes, int n_in,
                              void* d_out, int out_size, void* d_ws, size_t ws_size,
                              hipStream_t stream) {
  const float* Zimg   = (const float*)d_in[0];
  const float* Zsnd   = (const float*)d_in[1];
  const int*   padidx = (const int*)d_in[2];
  // d_in[3] = pad_mask (unused; validity derived from pad_idx)
  // d_in[4] = attn_dims (constant 64)

  const int N    = in_sizes[1] / C_;     // rows in Z_snd
  const int Smax = in_sizes[2] / G_;     // padded sequence length (== 256)

  float* z     = (float*)d_ws;                       // B*C fp32
  float* attnW = z + B_ * C_;                        // G*SMX*B_ fp32 = 4 MB
  float* Mimg  = (float*)d_out;
  float* Msnd  = Mimg + (size_t)G_ * B_ * CV;

  meanpool_kernel<<<(B_ * C_) / 4, 256, 0, stream>>>(Zimg, z);
  score_kernel<<<G_ * 2, 256, 0, stream>>>(Zsnd, padidx, z, attnW, Smax, N);
  out_kernel<<<G_ * 4, 256, 0, stream>>>(Zsnd, padidx, attnW, z, Mimg, Msnd, Smax, N);
}